// Round 2
// baseline (1272.179 us; speedup 1.0000x reference)
//
#include <hip/hip_runtime.h>
#include <math.h>

#define MODE_PLAIN 0
#define MODE_SC 1
#define MODE_TR 2

// ---------------- block reduction helper (256 threads, 2 values) ----------
__device__ __forceinline__ void breduce2(float &a, float &b, float* lds, int t) {
    #pragma unroll
    for (int off = 32; off; off >>= 1) {
        a += __shfl_xor(a, off, 64);
        b += __shfl_xor(b, off, 64);
    }
    __syncthreads();
    if ((t & 63) == 0) { lds[t >> 6] = a; lds[4 + (t >> 6)] = b; }
    __syncthreads();
    a = lds[0] + lds[1] + lds[2] + lds[3];
    b = lds[4] + lds[5] + lds[6] + lds[7];
}

// ---------------- init: copy res lower half ---------------------------------
__global__ __launch_bounds__(256) void init_kernel(const float* __restrict__ x0,
                                                   float* __restrict__ out) {
    int fi = blockIdx.x * 256 + threadIdx.x;     // 2,097,152 float4s
    int b = fi >> 18;                            // / 262144
    int r = fi & 262143;
    const float4* src = (const float4*)x0;
    float4* dst = (float4*)out;
    dst[(size_t)b * 524288 + r] = src[(size_t)b * 524288 + r];
}

// ---------------- generic 256x256 weight GEMM: Y[b,o,n] = W@X + bias -------
// tile: 128 o x 64 n, micro 8x4, K = 256 in 4 steps of 64
__global__ __launch_bounds__(256) void gemm_oc(
    const float* __restrict__ Wm,   // [256][256]
    const float* __restrict__ bias, // [256]
    const float* __restrict__ X,    // [b][c][n]
    int ldX, long long bsX,
    float* __restrict__ Y, int ldY, long long bsY,
    int mode, const float* __restrict__ x0full, float* __restrict__ dout,
    float* __restrict__ jpart)
{
    __shared__ float Ws[128][65];
    __shared__ __align__(16) float Xs[64][68];
    __shared__ float red[8];
    const int t = threadIdx.x;
    const int b = blockIdx.z;
    const int o0 = blockIdx.y * 128;
    const int n0 = blockIdx.x * 64;
    const int tx = t & 15, ty = t >> 4;

    float acc[8][4];
    #pragma unroll
    for (int i = 0; i < 8; i++)
        #pragma unroll
        for (int j = 0; j < 4; j++) acc[i][j] = 0.0f;

    for (int kb = 0; kb < 4; kb++) {
        #pragma unroll
        for (int i = 0; i < 32; i++) {
            int idx = t + 256 * i;
            int o = idx >> 6, kk = idx & 63;
            Ws[o][kk] = Wm[(size_t)(o0 + o) * 256 + kb * 64 + kk];
        }
        #pragma unroll
        for (int i = 0; i < 16; i++) {
            int idx = t + 256 * i;
            int kk = idx >> 6, n = idx & 63;
            Xs[kk][n] = X[(size_t)b * bsX + (size_t)(kb * 64 + kk) * ldX + n0 + n];
        }
        __syncthreads();
        #pragma unroll 4
        for (int kk = 0; kk < 64; kk++) {
            const float4 bv = *(const float4*)&Xs[kk][tx * 4];
            #pragma unroll
            for (int i = 0; i < 8; i++) {
                const float a = Ws[ty * 8 + i][kk];
                acc[i][0] += a * bv.x; acc[i][1] += a * bv.y;
                acc[i][2] += a * bv.z; acc[i][3] += a * bv.w;
            }
        }
        __syncthreads();
    }

    float ssum = 0.0f;
    #pragma unroll
    for (int i = 0; i < 8; i++) {
        const int o = o0 + ty * 8 + i;
        const float bia = bias[o];
        float4 val;
        val.x = acc[i][0] + bia; val.y = acc[i][1] + bia;
        val.z = acc[i][2] + bia; val.w = acc[i][3] + bia;
        const int n = n0 + tx * 4;
        if (mode == MODE_PLAIN) {
            *(float4*)&Y[(size_t)b * bsY + (size_t)o * ldY + n] = val;
        } else {
            const size_t addr = (size_t)b * 2097152 + (size_t)(256 + o) * 4096 + n;
            if (mode == MODE_SC) {
                *(float4*)&dout[addr] = val;
            } else {
                const float4 s4 = *(const float4*)&dout[addr];
                const float4 x4 = *(const float4*)&x0full[addr];
                float4 res;
                res.x = x4.x * expf(s4.x) + val.x;
                res.y = x4.y * expf(s4.y) + val.y;
                res.z = x4.z * expf(s4.z) + val.z;
                res.w = x4.w * expf(s4.w) + val.w;
                *(float4*)&dout[addr] = res;
                ssum += s4.x + s4.y + s4.z + s4.w;
            }
        }
    }
    if (mode == MODE_TR) {
        float dummy = 0.0f;
        breduce2(ssum, dummy, red, t);
        // deterministic per-block partial (no atomics, no zero-init dependence)
        if (t == 0) jpart[b * 128 + blockIdx.y * 64 + blockIdx.x] = ssum;
    }
}

// ---------------- final jac reduction: 8 blocks x 128 threads ---------------
__global__ __launch_bounds__(128) void jac_reduce(const float* __restrict__ jpart,
                                                  float* __restrict__ out) {
    __shared__ float red[2];
    const int b = blockIdx.x, t = threadIdx.x;
    float v = jpart[b * 128 + t];
    #pragma unroll
    for (int off = 32; off; off >>= 1) v += __shfl_xor(v, off, 64);
    if ((t & 63) == 0) red[t >> 6] = v;
    __syncthreads();
    if (t == 0) out[16777216 + b] = red[0] + red[1];
}

// ---------------- offset branch: dwconv4x4s4 -> LN -> GELU -> pw -> pos ----
__global__ __launch_bounds__(256) void offset_kernel(
    const float* __restrict__ q,     // [b][256][4096]
    const float* __restrict__ dw_w, const float* __restrict__ dw_b,
    const float* __restrict__ ln_g, const float* __restrict__ ln_b,
    const float* __restrict__ pw_w,  // [2][256]
    float* __restrict__ pos)         // [b][256][2]
{
    __shared__ float red[8];
    const int wk = blockIdx.x, hk = blockIdx.y, b = blockIdx.z;
    const int c = threadIdx.x;
    const float* qp = q + (size_t)(b * 256 + c) * 4096 + (hk * 4) * 64 + wk * 4;
    float accv = dw_b[c];
    #pragma unroll
    for (int p = 0; p < 4; p++) {
        const float4 r = *(const float4*)(qp + p * 64);
        const float4 w = *(const float4*)(dw_w + c * 16 + p * 4);
        accv += r.x * w.x + r.y * w.y + r.z * w.z + r.w * w.w;
    }
    float a = accv, sq = accv * accv;
    breduce2(a, sq, red, c);
    const float mu = a * (1.0f / 256.0f);
    const float var = sq * (1.0f / 256.0f) - mu * mu;
    float nrm = (accv - mu) * rsqrtf(var + 1e-5f) * ln_g[c] + ln_b[c];
    const float act = 0.5f * nrm * (1.0f + erff(nrm * 0.70710678118654752f));
    float v0 = pw_w[c] * act;
    float v1 = pw_w[256 + c] * act;
    breduce2(v0, v1, red, c);
    if (c == 0) {
        const float refy = (0.5f + hk) * (2.0f / 15.0f) - 1.0f;
        const float refx = (0.5f + wk) * (2.0f / 15.0f) - 1.0f;
        const float py = fminf(fmaxf(v0 + refy, -1.0f), 1.0f);
        const float px = fminf(fmaxf(v1 + refx, -1.0f), 1.0f);
        const int n = hk * 16 + wk;
        pos[(b * 256 + n) * 2] = py;
        pos[(b * 256 + n) * 2 + 1] = px;
    }
}

// ---------------- bilinear sample x at deformable points -------------------
__global__ __launch_bounds__(256) void sample_kernel(
    const float* __restrict__ x0,   // full [b][512][4096]
    const float* __restrict__ pos,  // [b][256][2]
    float* __restrict__ xs)         // [b][256][256]
{
    const int n = blockIdx.x, b = blockIdx.y, c = threadIdx.x;
    const float py = pos[(b * 256 + n) * 2];
    const float px = pos[(b * 256 + n) * 2 + 1];
    const float x = (px + 1.0f) * 31.5f;   // *0.5*(64-1)
    const float y = (py + 1.0f) * 31.5f;
    const float xf = floorf(x), yf = floorf(y);
    const float wx = x - xf, wy = y - yf;
    const int xi0 = min(max((int)xf, 0), 63);
    const int xi1 = min(xi0 + 1, 63);
    const int yi0 = min(max((int)yf, 0), 63);
    const int yi1 = min(yi0 + 1, 63);
    const float* base = x0 + (size_t)b * 2097152 + (size_t)c * 4096;
    const float v00 = base[yi0 * 64 + xi0], v01 = base[yi0 * 64 + xi1];
    const float v10 = base[yi1 * 64 + xi0], v11 = base[yi1 * 64 + xi1];
    xs[(size_t)(b * 256 + c) * 256 + n] =
        v00 * (1 - wx) * (1 - wy) + v01 * wx * (1 - wy) +
        v10 * (1 - wx) * wy + v11 * wx * wy;
}

// ---------------- fused attention: QK^T + RPE, softmax, PV -----------------
// block: 256 thr, one (b, h, 16-m tile). k LDS [c][n-chunk], v LDS [n][c].
// NOTE: q and obuf ALIAS (same buffer) — no __restrict__ on them.
__global__ __launch_bounds__(256) void attn_kernel(
    const float* q,                 // [b][256][4096]
    const float* __restrict__ kbuf, // [b][256][256]
    const float* __restrict__ vbuf, // [b][256][256]
    const float* __restrict__ pos,  // [b][256][2]
    const float* __restrict__ rpe,  // [4][127][127]
    float* obuf)                    // [b][256][4096] (aliases q)
{
    __shared__ __align__(16) float kv[8704];   // k: [64][132] / vT: [128][68]
    __shared__ __align__(16) float qs[1280];   // [c][m] pad 20
    __shared__ __align__(16) float pl[4160];   // [m][n] pad 260
    __shared__ float posy[256];
    __shared__ float posx[256];
    __shared__ float invs[16];
    const int t = threadIdx.x;
    const int m0 = blockIdx.x * 16;
    const int h = blockIdx.y;
    const int b = blockIdx.z;
    const size_t qbase = (size_t)(b * 256 + h * 64) * 4096;
    const size_t kbase = (size_t)(b * 256 + h * 64) * 256;

    #pragma unroll
    for (int i = 0; i < 4; i++) {
        int idx = t + 256 * i;
        int m = idx & 15, c = idx >> 4;
        qs[c * 20 + m] = q[qbase + (size_t)c * 4096 + m0 + m];
    }
    posy[t] = pos[(b * 256 + t) * 2];
    posx[t] = pos[(b * 256 + t) * 2 + 1];
    __syncthreads();

    const float* rp = rpe + h * 16129;
    {
        const int tmq = t >> 6;           // wave id -> m group (uniform)
        const int tn = t & 63;
        const int mb = tmq * 4;
        const int nn2 = tn * 2;
        for (int ch = 0; ch < 2; ch++) {
            const int nb = ch * 128;
            #pragma unroll
            for (int i = 0; i < 32; i++) {
                int idx = t + 256 * i;
                int c2 = idx >> 7, nn = idx & 127;
                kv[c2 * 132 + nn] = kbuf[kbase + (size_t)c2 * 256 + nb + nn];
            }
            __syncthreads();
            float a00=0,a01=0,a10=0,a11=0,a20=0,a21=0,a30=0,a31=0;
            #pragma unroll 8
            for (int c2 = 0; c2 < 64; c2++) {
                const float4 qv = *(const float4*)&qs[c2 * 20 + mb];
                const float2 k2 = *(const float2*)&kv[c2 * 132 + nn2];
                a00 += qv.x * k2.x; a01 += qv.x * k2.y;
                a10 += qv.y * k2.x; a11 += qv.y * k2.y;
                a20 += qv.z * k2.x; a21 += qv.z * k2.y;
                a30 += qv.w * k2.x; a31 += qv.w * k2.y;
            }
            float accs[4][2] = {{a00,a01},{a10,a11},{a20,a21},{a30,a31}};
            #pragma unroll
            for (int i = 0; i < 4; i++) {
                const int mg = m0 + mb + i;
                const float qy = (float)(mg >> 6) * (2.0f / 63.0f) - 1.0f;
                const float qx = (float)(mg & 63) * (2.0f / 63.0f) - 1.0f;
                #pragma unroll
                for (int j = 0; j < 2; j++) {
                    const int ng = nb + nn2 + j;
                    const float dx2 = (qx - posx[ng]) * 0.5f;
                    const float dy2 = (qy - posy[ng]) * 0.5f;
                    const float xx = (dx2 + 1.0f) * 63.0f;   // *0.5*(127-1)
                    const float yy = (dy2 + 1.0f) * 63.0f;
                    const float xf = floorf(xx), yf = floorf(yy);
                    const float wx = xx - xf, wy = yy - yf;
                    const int xi0 = min(max((int)xf, 0), 126);
                    const int xi1 = min(xi0 + 1, 126);
                    const int yi0 = min(max((int)yf, 0), 126);
                    const int yi1 = min(yi0 + 1, 126);
                    const float r00 = rp[yi0 * 127 + xi0], r01 = rp[yi0 * 127 + xi1];
                    const float r10 = rp[yi1 * 127 + xi0], r11 = rp[yi1 * 127 + xi1];
                    const float rv = r00 * (1 - wx) * (1 - wy) + r01 * wx * (1 - wy)
                                   + r10 * (1 - wx) * wy + r11 * wx * wy;
                    pl[(mb + i) * 260 + ng] = accs[i][j] * 0.125f + rv;
                }
            }
            __syncthreads();
        }
    }

    // softmax over n=256 per row m (16 lanes per row)
    {
        const int r = t >> 4, s = t & 15;
        float vals[16];
        float mx = -1e30f;
        #pragma unroll
        for (int jj = 0; jj < 16; jj++) {
            vals[jj] = pl[r * 260 + s + 16 * jj];
            mx = fmaxf(mx, vals[jj]);
        }
        #pragma unroll
        for (int off = 8; off; off >>= 1) mx = fmaxf(mx, __shfl_xor(mx, off, 16));
        float sum = 0.0f;
        #pragma unroll
        for (int jj = 0; jj < 16; jj++) {
            const float e = expf(vals[jj] - mx);
            pl[r * 260 + s + 16 * jj] = e;
            sum += e;
        }
        #pragma unroll
        for (int off = 8; off; off >>= 1) sum += __shfl_xor(sum, off, 16);
        if (s == 0) invs[r] = 1.0f / sum;
    }
    __syncthreads();

    // PV: thread -> 4 channels x 1 m
    {
        const int tc = t & 15, tm = t >> 4;
        float o0 = 0, o1 = 0, o2 = 0, o3 = 0;
        for (int ch = 0; ch < 2; ch++) {
            const int nb = ch * 128;
            #pragma unroll
            for (int i = 0; i < 32; i++) {
                int idx = t + 256 * i;
                int c2 = idx >> 7, nn = idx & 127;
                kv[nn * 68 + c2] = vbuf[kbase + (size_t)c2 * 256 + nb + nn];
            }
            __syncthreads();
            #pragma unroll 8
            for (int nn = 0; nn < 128; nn++) {
                const float4 v4 = *(const float4*)&kv[nn * 68 + tc * 4];
                const float p = pl[tm * 260 + nb + nn];
                o0 += v4.x * p; o1 += v4.y * p; o2 += v4.z * p; o3 += v4.w * p;
            }
            __syncthreads();
        }
        const float inv = invs[tm];
        const size_t ob = qbase + (size_t)(tc * 4) * 4096 + m0 + tm;
        obuf[ob]         = o0 * inv;
        obuf[ob + 4096]  = o1 * inv;
        obuf[ob + 8192]  = o2 * inv;
        obuf[ob + 12288] = o3 * inv;
    }
}

// ---------------- host launcher --------------------------------------------
extern "C" void kernel_launch(void* const* d_in, const int* in_sizes, int n_in,
                              void* d_out, int out_size, void* d_ws, size_t ws_size,
                              hipStream_t stream) {
    const float* x0 = (const float*)d_in[0];
    float* out = (float*)d_out;
    float* ws = (float*)d_ws;
    float* qo    = ws;                 // 8,388,608 floats (q, later aliased o)
    float* xs    = ws + 8388608;       //   524,288
    float* kbf   = ws + 8912896;       //   524,288
    float* vbf   = ws + 9437184;       //   524,288
    float* pos   = ws + 9961472;       //     4,096
    float* jpart = ws + 9965568;       //     1,024

    init_kernel<<<8192, 256, 0, stream>>>(x0, out);

    for (int pass = 0; pass < 2; pass++) {
        const int pb = 1 + 14 * pass;
        const float* dw_w = (const float*)d_in[pb + 0];
        const float* dw_b = (const float*)d_in[pb + 1];
        const float* ln_g = (const float*)d_in[pb + 2];
        const float* ln_b = (const float*)d_in[pb + 3];
        const float* pw_w = (const float*)d_in[pb + 4];
        const float* wq   = (const float*)d_in[pb + 5];
        const float* bq   = (const float*)d_in[pb + 6];
        const float* wk   = (const float*)d_in[pb + 7];
        const float* bk   = (const float*)d_in[pb + 8];
        const float* wv   = (const float*)d_in[pb + 9];
        const float* bv   = (const float*)d_in[pb + 10];
        const float* wo   = (const float*)d_in[pb + 11];
        const float* bo   = (const float*)d_in[pb + 12];
        const float* rpe  = (const float*)d_in[pb + 13];

        // q = wq @ x_lower + bq
        gemm_oc<<<dim3(64, 2, 8), 256, 0, stream>>>(
            wq, bq, x0, 4096, 2097152LL, qo, 4096, 1048576LL,
            MODE_PLAIN, nullptr, nullptr, nullptr);
        // offsets -> pos
        offset_kernel<<<dim3(16, 16, 8), 256, 0, stream>>>(
            qo, dw_w, dw_b, ln_g, ln_b, pw_w, pos);
        // deformable sampling
        sample_kernel<<<dim3(256, 8), 256, 0, stream>>>(x0, pos, xs);
        // k, v projections
        gemm_oc<<<dim3(4, 2, 8), 256, 0, stream>>>(
            wk, bk, xs, 256, 65536LL, kbf, 256, 65536LL,
            MODE_PLAIN, nullptr, nullptr, nullptr);
        gemm_oc<<<dim3(4, 2, 8), 256, 0, stream>>>(
            wv, bv, xs, 256, 65536LL, vbf, 256, 65536LL,
            MODE_PLAIN, nullptr, nullptr, nullptr);
        // fused attention (o aliases q)
        attn_kernel<<<dim3(256, 4, 8), 256, 0, stream>>>(
            qo, kbf, vbf, pos, rpe, qo);
        // wo projection with fused epilogue
        gemm_oc<<<dim3(64, 2, 8), 256, 0, stream>>>(
            wo, bo, qo, 4096, 1048576LL, nullptr, 0, 0LL,
            pass == 0 ? MODE_SC : MODE_TR, x0, out, jpart);
    }
    // deterministic jac finalize (plain stores, fixed-order reduction)
    jac_reduce<<<8, 128, 0, stream>>>(jpart, out);
}

// Round 5
// 804.830 us; speedup vs baseline: 1.5807x; 1.5807x over previous
//
#include <hip/hip_runtime.h>
#include <math.h>

typedef __bf16 bf16;
typedef __attribute__((ext_vector_type(8))) __bf16 bf16x8;
typedef __attribute__((ext_vector_type(4))) __bf16 bf16x4;
typedef __attribute__((ext_vector_type(4))) float floatx4;

#define MFMA16(a, b, c) __builtin_amdgcn_mfma_f32_16x16x32_bf16((a), (b), (c), 0, 0, 0)

// GEMM modes: 0=Q (fp32 q into out-lower + bf16 qbfT), 1=K (bf16 [n][o]),
//             2=V (bf16 [o][n]), 3=SC (s into out-upper), 4=TR (res + jac)
// Modes 0-2 take fp32 channel-major A and split hi/lo on the fly (3-product MFMA).
// Modes 3-4 take bf16 pixel-major A, weights split (2-product MFMA).

__device__ __forceinline__ void breduce1(float &a, float* lds, int t) {
    #pragma unroll
    for (int off = 32; off; off >>= 1) a += __shfl_xor(a, off, 64);
    __syncthreads();
    if ((t & 63) == 0) lds[t >> 6] = a;
    __syncthreads();
    a = lds[0] + lds[1] + lds[2] + lds[3];
}

// ---------------- init: copy res lower half --------------------------------
__global__ __launch_bounds__(256) void init_kernel(const float* __restrict__ x0,
                                                   float* __restrict__ out) {
    int fi = blockIdx.x * 256 + threadIdx.x;
    int b = fi >> 18;
    int r = fi & 262143;
    const float4* src = (const float4*)x0;
    float4* dst = (float4*)out;
    dst[(size_t)b * 524288 + r] = src[(size_t)b * 524288 + r];
}

// ---------------- weight fp32 -> bf16 hi/lo pairs (8 matrices) -------------
__global__ __launch_bounds__(256) void wconv(
    const float* __restrict__ w0, const float* __restrict__ w1,
    const float* __restrict__ w2, const float* __restrict__ w3,
    const float* __restrict__ w4, const float* __restrict__ w5,
    const float* __restrict__ w6, const float* __restrict__ w7,
    bf16* __restrict__ dst) {
    const int wi = blockIdx.y;
    const float* src = wi == 0 ? w0 : wi == 1 ? w1 : wi == 2 ? w2 : wi == 3 ? w3
                     : wi == 4 ? w4 : wi == 5 ? w5 : wi == 6 ? w6 : w7;
    const int i = blockIdx.x * 1024 + threadIdx.x * 4;
    const float4 v = *(const float4*)(src + i);
    bf16x4 h, l;
    #pragma unroll
    for (int j = 0; j < 4; j++) {
        const float f = ((const float*)&v)[j];
        const bf16 hb = (bf16)f;
        h[j] = hb;
        l[j] = (bf16)(f - (float)hb);
    }
    *(bf16x4*)(dst + (size_t)wi * 65536 + i) = h;
    *(bf16x4*)(dst + (size_t)(8 + wi) * 65536 + i) = l;
}

// ---------------- split-precision MFMA GEMM --------------------------------
// D[n][o] = A[n][k] * W[o][k]^T + bias.  tile 128n x 128o, K=256 in 8x32.
template <int MODE>
__global__ __launch_bounds__(256) void gemm_mfma(
    const void* __restrict__ Aptr, int ldA, long long bsA,
    const bf16* __restrict__ Whi, const bf16* __restrict__ Wlo,
    const float* __restrict__ bias,
    bf16* __restrict__ outb,
    float* outf,
    const float* __restrict__ x0full,
    float* __restrict__ jpart)
{
    constexpr bool ASPLIT = (MODE <= 2);
    __shared__ __align__(16) bf16 As_hi[128 * 40];
    __shared__ __align__(16) bf16 As_lo[ASPLIT ? 128 * 40 : 1];
    __shared__ __align__(16) bf16 Bs_hi[128 * 40];
    __shared__ __align__(16) bf16 Bs_lo[128 * 40];
    __shared__ float red[4];
    const int t = threadIdx.x;
    const int b = blockIdx.z;
    const int n0 = blockIdx.x * 128;
    const int o0 = blockIdx.y * 128;
    const int w = t >> 6, l = t & 63;
    const int wr = w & 1, wc = w >> 1;
    const int lr = l & 15, lq = l >> 4;

    floatx4 acc[4][4] = {};

    for (int kb = 0; kb < 8; kb++) {
        // stage A
        if (ASPLIT) {
            const float* Af = (const float*)Aptr + (size_t)b * bsA;
            #pragma unroll
            for (int s = 0; s < 4; s++) {
                const int kk = s * 8 + (t >> 5);
                const int n = (t & 31) * 4;
                const float4 v = *(const float4*)(Af + (size_t)(kb * 32 + kk) * ldA + n0 + n);
                #pragma unroll
                for (int j = 0; j < 4; j++) {
                    const float f = ((const float*)&v)[j];
                    const bf16 hb = (bf16)f;
                    As_hi[(n + j) * 40 + kk] = hb;
                    As_lo[(n + j) * 40 + kk] = (bf16)(f - (float)hb);
                }
            }
        } else {
            const bf16* Ab = (const bf16*)Aptr + (size_t)b * bsA;
            #pragma unroll
            for (int s = 0; s < 2; s++) {
                const int idx = t + 256 * s;
                const int row = idx >> 2, seg = idx & 3;
                *(bf16x8*)(As_hi + row * 40 + seg * 8) =
                    *(const bf16x8*)(Ab + (size_t)(n0 + row) * 256 + kb * 32 + seg * 8);
            }
        }
        // stage W hi/lo
        #pragma unroll
        for (int s = 0; s < 2; s++) {
            const int idx = t + 256 * s;
            const int row = idx >> 2, seg = idx & 3;
            *(bf16x8*)(Bs_hi + row * 40 + seg * 8) =
                *(const bf16x8*)(Whi + (size_t)(o0 + row) * 256 + kb * 32 + seg * 8);
            *(bf16x8*)(Bs_lo + row * 40 + seg * 8) =
                *(const bf16x8*)(Wlo + (size_t)(o0 + row) * 256 + kb * 32 + seg * 8);
        }
        __syncthreads();
        bf16x8 ah[4], al[4], bh[4], bl[4];
        #pragma unroll
        for (int f = 0; f < 4; f++) {
            ah[f] = *(const bf16x8*)(As_hi + (wr * 64 + f * 16 + lr) * 40 + lq * 8);
            if (ASPLIT)
                al[f] = *(const bf16x8*)(As_lo + (wr * 64 + f * 16 + lr) * 40 + lq * 8);
            bh[f] = *(const bf16x8*)(Bs_hi + (wc * 64 + f * 16 + lr) * 40 + lq * 8);
            bl[f] = *(const bf16x8*)(Bs_lo + (wc * 64 + f * 16 + lr) * 40 + lq * 8);
        }
        #pragma unroll
        for (int i = 0; i < 4; i++)
            #pragma unroll
            for (int j = 0; j < 4; j++) {
                acc[i][j] = MFMA16(ah[i], bh[j], acc[i][j]);
                acc[i][j] = MFMA16(ah[i], bl[j], acc[i][j]);
                if (ASPLIT) acc[i][j] = MFMA16(al[i], bh[j], acc[i][j]);
            }
        __syncthreads();
    }

    float ssum = 0.0f;
    #pragma unroll
    for (int i = 0; i < 4; i++) {
        #pragma unroll
        for (int j = 0; j < 4; j++) {
            const int o_g = o0 + wc * 64 + j * 16 + lr;
            const int n_b = n0 + wr * 64 + i * 16 + lq * 4;
            const float bia = bias[o_g];
            floatx4 val = acc[i][j];
            val[0] += bia; val[1] += bia; val[2] += bia; val[3] += bia;
            if (MODE == 0) {
                *(floatx4*)(outf + (size_t)b * 2097152 + (size_t)o_g * 4096 + n_b) = val;
                #pragma unroll
                for (int r = 0; r < 4; r++)
                    outb[((size_t)b * 4096 + n_b + r) * 256 + o_g] = (bf16)val[r];
            } else if (MODE == 1) {
                #pragma unroll
                for (int r = 0; r < 4; r++)
                    outb[((size_t)b * 256 + n_b + r) * 256 + o_g] = (bf16)val[r];
            } else if (MODE == 2) {
                bf16x4 pv;
                pv[0] = (bf16)val[0]; pv[1] = (bf16)val[1];
                pv[2] = (bf16)val[2]; pv[3] = (bf16)val[3];
                *(bf16x4*)(outb + ((size_t)b * 256 + o_g) * 256 + n_b) = pv;
            } else {
                const size_t addr = (size_t)b * 2097152 + (size_t)(256 + o_g) * 4096 + n_b;
                if (MODE == 3) {
                    *(floatx4*)(outf + addr) = val;
                } else {
                    const floatx4 s4 = *(const floatx4*)(outf + addr);
                    const floatx4 x4 = *(const floatx4*)(x0full + addr);
                    floatx4 res;
                    #pragma unroll
                    for (int r = 0; r < 4; r++) res[r] = x4[r] * expf(s4[r]) + val[r];
                    *(floatx4*)(outf + addr) = res;
                    ssum += s4[0] + s4[1] + s4[2] + s4[3];
                }
            }
        }
    }
    if (MODE == 4) {
        breduce1(ssum, red, t);
        if (t == 0) jpart[b * 64 + blockIdx.y * 32 + blockIdx.x] = ssum;
    }
}

// ---------------- jac finalize ---------------------------------------------
__global__ __launch_bounds__(64) void jac_reduce(const float* __restrict__ jpart,
                                                 float* __restrict__ out) {
    const int b = blockIdx.x, t = threadIdx.x;
    float v = jpart[b * 64 + t];
    #pragma unroll
    for (int off = 32; off; off >>= 1) v += __shfl_xor(v, off, 64);
    if (t == 0) out[16777216 + b] = v;
}

// ---------------- offset branch (q fp32 lives in out-lower) ----------------
__global__ __launch_bounds__(256) void offset_kernel(
    const float* __restrict__ q,
    const float* __restrict__ dw_w, const float* __restrict__ dw_b,
    const float* __restrict__ ln_g, const float* __restrict__ ln_b,
    const float* __restrict__ pw_w,
    float* __restrict__ pos)
{
    __shared__ float red[8];
    const int wk = blockIdx.x, hk = blockIdx.y, b = blockIdx.z;
    const int c = threadIdx.x;
    const float* qp = q + (size_t)b * 2097152 + (size_t)c * 4096 + (hk * 4) * 64 + wk * 4;
    float accv = dw_b[c];
    #pragma unroll
    for (int p = 0; p < 4; p++) {
        const float4 r = *(const float4*)(qp + p * 64);
        const float4 w = *(const float4*)(dw_w + c * 16 + p * 4);
        accv += r.x * w.x + r.y * w.y + r.z * w.z + r.w * w.w;
    }
    float a = accv, sq = accv * accv;
    #pragma unroll
    for (int off = 32; off; off >>= 1) {
        a += __shfl_xor(a, off, 64);
        sq += __shfl_xor(sq, off, 64);
    }
    __syncthreads();
    if ((c & 63) == 0) { red[c >> 6] = a; red[4 + (c >> 6)] = sq; }
    __syncthreads();
    a = red[0] + red[1] + red[2] + red[3];
    sq = red[4] + red[5] + red[6] + red[7];
    const float mu = a * (1.0f / 256.0f);
    const float var = sq * (1.0f / 256.0f) - mu * mu;
    float nrm = (accv - mu) * rsqrtf(var + 1e-5f) * ln_g[c] + ln_b[c];
    const float act = 0.5f * nrm * (1.0f + erff(nrm * 0.70710678118654752f));
    float v0 = pw_w[c] * act;
    float v1 = pw_w[256 + c] * act;
    #pragma unroll
    for (int off = 32; off; off >>= 1) {
        v0 += __shfl_xor(v0, off, 64);
        v1 += __shfl_xor(v1, off, 64);
    }
    __syncthreads();
    if ((c & 63) == 0) { red[c >> 6] = v0; red[4 + (c >> 6)] = v1; }
    __syncthreads();
    if (c == 0) {
        v0 = red[0] + red[1] + red[2] + red[3];
        v1 = red[4] + red[5] + red[6] + red[7];
        const float refy = (0.5f + hk) * (2.0f / 15.0f) - 1.0f;
        const float refx = (0.5f + wk) * (2.0f / 15.0f) - 1.0f;
        const float py = fminf(fmaxf(v0 + refy, -1.0f), 1.0f);
        const float px = fminf(fmaxf(v1 + refx, -1.0f), 1.0f);
        const int n = hk * 16 + wk;
        pos[(b * 256 + n) * 2] = py;
        pos[(b * 256 + n) * 2 + 1] = px;
    }
}

// ---------------- bilinear sample -> xs fp32 channel-major [b][c][n] -------
__global__ __launch_bounds__(256) void sample_kernel(
    const float* __restrict__ x0,
    const float* __restrict__ pos,
    float* __restrict__ xs)
{
    const int c = threadIdx.x, j0 = blockIdx.x * 4, b = blockIdx.y;
    const float* base = x0 + (size_t)b * 2097152 + (size_t)c * 4096;
    float4 outv;
    #pragma unroll
    for (int j = 0; j < 4; j++) {
        const int n = j0 + j;
        const float py = pos[(b * 256 + n) * 2];
        const float px = pos[(b * 256 + n) * 2 + 1];
        const float x = (px + 1.0f) * 31.5f;
        const float y = (py + 1.0f) * 31.5f;
        const float xf = floorf(x), yf = floorf(y);
        const float wx = x - xf, wy = y - yf;
        const int xi0 = min(max((int)xf, 0), 63);
        const int xi1 = min(xi0 + 1, 63);
        const int yi0 = min(max((int)yf, 0), 63);
        const int yi1 = min(yi0 + 1, 63);
        const float v00 = base[yi0 * 64 + xi0], v01 = base[yi0 * 64 + xi1];
        const float v10 = base[yi1 * 64 + xi0], v11 = base[yi1 * 64 + xi1];
        ((float*)&outv)[j] = v00 * (1 - wx) * (1 - wy) + v01 * wx * (1 - wy) +
                             v10 * (1 - wx) * wy + v11 * wx * wy;
    }
    *(float4*)(xs + ((size_t)b * 256 + c) * 256 + j0) = outv;
}

// ---------------- fused MFMA attention -------------------------------------
__global__ __launch_bounds__(256) void attn_mfma(
    const bf16* qbfT,               // [b][4096][256]
    const bf16* __restrict__ kT,    // [b][256][256] pixel-major
    const bf16* __restrict__ vb,    // [b][256 c][256 n] channel-major
    const float* __restrict__ pos,
    const float* __restrict__ rpe,
    bf16* obfT)                     // aliases qbfT
{
    __shared__ __align__(16) bf16 kvt[18432];      // K: [256 n][72] / V: [64 c][264]
    __shared__ __align__(16) bf16 pl[4 * 16 * 264];
    __shared__ float posy[256], posx[256];
    const int t = threadIdx.x;
    const int w = t >> 6, l = t & 63;
    const int lr = l & 15, lq = l >> 4;
    const int m_base = blockIdx.x * 64 + w * 16;
    const int h = blockIdx.y, b = blockIdx.z;

    posy[t] = pos[(b * 256 + t) * 2];
    posx[t] = pos[(b * 256 + t) * 2 + 1];

    const bf16* qrow = qbfT + ((size_t)b * 4096 + m_base + lr) * 256 + h * 64;
    bf16x8 qf0 = *(const bf16x8*)(qrow + lq * 8);
    bf16x8 qf1 = *(const bf16x8*)(qrow + 32 + lq * 8);

    #pragma unroll
    for (int i = 0; i < 8; i++) {
        const int idx = t + 256 * i;
        const int n = idx >> 3, seg = idx & 7;
        *(bf16x8*)(kvt + n * 72 + seg * 8) =
            *(const bf16x8*)(kT + ((size_t)b * 256 + n) * 256 + h * 64 + seg * 8);
    }
    __syncthreads();

    floatx4 lg[16];
    #pragma unroll
    for (int nf = 0; nf < 16; nf++) {
        const bf16x8 k0 = *(const bf16x8*)(kvt + (nf * 16 + lr) * 72 + lq * 8);
        const bf16x8 k1 = *(const bf16x8*)(kvt + (nf * 16 + lr) * 72 + 32 + lq * 8);
        floatx4 a = {};
        a = MFMA16(qf0, k0, a);
        a = MFMA16(qf1, k1, a);
        lg[nf] = a;
    }

    const float* rp = rpe + h * 16129;
    float qyv[4], qxv[4];
    #pragma unroll
    for (int r = 0; r < 4; r++) {
        const int mg = m_base + lq * 4 + r;
        qyv[r] = (float)(mg >> 6) * (2.0f / 63.0f) - 1.0f;
        qxv[r] = (float)(mg & 63) * (2.0f / 63.0f) - 1.0f;
    }
    #pragma unroll
    for (int nf = 0; nf < 16; nf++) {
        const int n = nf * 16 + lr;
        const float px = posx[n], py = posy[n];
        #pragma unroll
        for (int r = 0; r < 4; r++) {
            const float dx2 = (qxv[r] - px) * 0.5f;
            const float dy2 = (qyv[r] - py) * 0.5f;
            const float xx = (dx2 + 1.0f) * 63.0f;
            const float yy = (dy2 + 1.0f) * 63.0f;
            const float xf = floorf(xx), yf = floorf(yy);
            const float wx = xx - xf, wy = yy - yf;
            const int xi0 = min(max((int)xf, 0), 126);
            const int xi1 = min(xi0 + 1, 126);
            const int yi0 = min(max((int)yf, 0), 126);
            const int yi1 = min(yi0 + 1, 126);
            const float r00 = rp[yi0 * 127 + xi0], r01 = rp[yi0 * 127 + xi1];
            const float r10 = rp[yi1 * 127 + xi0], r11 = rp[yi1 * 127 + xi1];
            const float rv = r00 * (1 - wx) * (1 - wy) + r01 * wx * (1 - wy)
                           + r10 * (1 - wx) * wy + r11 * wx * wy;
            lg[nf][r] = lg[nf][r] * 0.125f + rv;
        }
    }

    float mx[4], inv[4];
    #pragma unroll
    for (int r = 0; r < 4; r++) {
        float m = -1e30f;
        #pragma unroll
        for (int nf = 0; nf < 16; nf++) m = fmaxf(m, lg[nf][r]);
        #pragma unroll
        for (int off = 1; off < 16; off <<= 1) m = fmaxf(m, __shfl_xor(m, off, 64));
        mx[r] = m;
    }
    #pragma unroll
    for (int r = 0; r < 4; r++) {
        float s = 0.0f;
        #pragma unroll
        for (int nf = 0; nf < 16; nf++) {
            const float e = expf(lg[nf][r] - mx[r]);
            lg[nf][r] = e;
            s += e;
        }
        #pragma unroll
        for (int off = 1; off < 16; off <<= 1) s += __shfl_xor(s, off, 64);
        inv[r] = 1.0f / s;
    }

    bf16* plw = pl + w * 16 * 264;
    #pragma unroll
    for (int nf = 0; nf < 16; nf++)
        #pragma unroll
        for (int r = 0; r < 4; r++)
            plw[(lq * 4 + r) * 264 + nf * 16 + lr] = (bf16)(lg[nf][r] * inv[r]);

    __syncthreads();

    #pragma unroll
    for (int i = 0; i < 8; i++) {
        const int idx = t + 256 * i;
        const int c = idx >> 5, seg = idx & 31;
        *(bf16x8*)(kvt + c * 264 + seg * 8) =
            *(const bf16x8*)(vb + ((size_t)b * 256 + h * 64 + c) * 256 + seg * 8);
    }
    __syncthreads();

    floatx4 oc[4] = {};
    #pragma unroll
    for (int kf = 0; kf < 8; kf++) {
        const bf16x8 pa = *(const bf16x8*)(plw + lr * 264 + kf * 32 + lq * 8);
        #pragma unroll
        for (int j = 0; j < 4; j++) {
            const bf16x8 vf = *(const bf16x8*)(kvt + (j * 16 + lr) * 264 + kf * 32 + lq * 8);
            oc[j] = MFMA16(pa, vf, oc[j]);
        }
    }

    #pragma unroll
    for (int j = 0; j < 4; j++)
        #pragma unroll
        for (int r = 0; r < 4; r++)
            obfT[((size_t)b * 4096 + m_base + lq * 4 + r) * 256 + h * 64 + j * 16 + lr]
                = (bf16)oc[j][r];
}

// ---------------- host launcher --------------------------------------------
extern "C" void kernel_launch(void* const* d_in, const int* in_sizes, int n_in,
                              void* d_out, int out_size, void* d_ws, size_t ws_size,
                              hipStream_t stream) {
    const float* x0 = (const float*)d_in[0];
    float* out = (float*)d_out;
    float* ws = (float*)d_ws;
    // ws layout (float units), total ~23.1 MB
    bf16* qbfT  = (bf16*)ws;                   // [8][4096][256] bf16 = 4,194,304 fl
    float* xsT  = ws + 4194304;                // [8][256][256] fp32  =   524,288 fl
    bf16* kTb   = (bf16*)(ws + 4718592);       // [8][256][256] bf16  =   262,144 fl
    bf16* vbb   = (bf16*)(ws + 4980736);       // [8][256][256] bf16  =   262,144 fl
    bf16* wbf   = (bf16*)(ws + 5242880);       // 16 x [256][256] bf16=   524,288 fl
    float* pos  = ws + 5767168;                // 4,096 fl
    float* jpart= ws + 5771264;                // 512 fl  (end 5,771,776)

    // weights -> bf16 hi/lo (hi at wi, lo at 8+wi; order sc q,k,v,o, tr q,k,v,o)
    wconv<<<dim3(64, 8), 256, 0, stream>>>(
        (const float*)d_in[6], (const float*)d_in[8], (const float*)d_in[10],
        (const float*)d_in[12], (const float*)d_in[20], (const float*)d_in[22],
        (const float*)d_in[24], (const float*)d_in[26], wbf);

    for (int pass = 0; pass < 2; pass++) {
        const int pb = 1 + 14 * pass;
        const float* dw_w = (const float*)d_in[pb + 0];
        const float* dw_b = (const float*)d_in[pb + 1];
        const float* ln_g = (const float*)d_in[pb + 2];
        const float* ln_b = (const float*)d_in[pb + 3];
        const float* pw_w = (const float*)d_in[pb + 4];
        const float* bq   = (const float*)d_in[pb + 6];
        const float* bk   = (const float*)d_in[pb + 8];
        const float* bv   = (const float*)d_in[pb + 10];
        const float* bo   = (const float*)d_in[pb + 12];
        const float* rpe  = (const float*)d_in[pb + 13];
        const bf16* wq_h = wbf + (size_t)(pass * 4 + 0) * 65536;
        const bf16* wk_h = wbf + (size_t)(pass * 4 + 1) * 65536;
        const bf16* wv_h = wbf + (size_t)(pass * 4 + 2) * 65536;
        const bf16* wo_h = wbf + (size_t)(pass * 4 + 3) * 65536;
        const bf16* wq_l = wq_h + 8 * 65536;
        const bf16* wk_l = wk_h + 8 * 65536;
        const bf16* wv_l = wv_h + 8 * 65536;
        const bf16* wo_l = wo_h + 8 * 65536;

        // q projection (split A from fp32 x0): fp32 q -> out-lower, bf16 -> qbfT
        gemm_mfma<0><<<dim3(32, 2, 8), 256, 0, stream>>>(
            x0, 4096, 2097152LL, wq_h, wq_l, bq, qbfT, out, nullptr, nullptr);
        // offsets (fp32)
        offset_kernel<<<dim3(16, 16, 8), 256, 0, stream>>>(
            out, dw_w, dw_b, ln_g, ln_b, pw_w, pos);
        // deformable sampling -> xs fp32 channel-major
        sample_kernel<<<dim3(64, 8), 256, 0, stream>>>(x0, pos, xsT);
        // k, v projections (split A from fp32 xs)
        gemm_mfma<1><<<dim3(2, 2, 8), 256, 0, stream>>>(
            xsT, 256, 65536LL, wk_h, wk_l, bk, kTb, nullptr, nullptr, nullptr);
        gemm_mfma<2><<<dim3(2, 2, 8), 256, 0, stream>>>(
            xsT, 256, 65536LL, wv_h, wv_l, bv, vbb, nullptr, nullptr, nullptr);
        // fused attention (o over qbfT)
        attn_mfma<<<dim3(64, 4, 8), 256, 0, stream>>>(
            qbfT, kTb, vbb, pos, rpe, qbfT);
        // wo projection + epilogue (A bf16, W split)
        if (pass == 0)
            gemm_mfma<3><<<dim3(32, 2, 8), 256, 0, stream>>>(
                qbfT, 256, 1048576LL, wo_h, wo_l, bo, nullptr, out, nullptr, nullptr);
        else
            gemm_mfma<4><<<dim3(32, 2, 8), 256, 0, stream>>>(
                qbfT, 256, 1048576LL, wo_h, wo_l, bo, nullptr, out, x0, jpart);
    }
    // restore out-lower (q scratch) to x0 lower
    init_kernel<<<8192, 256, 0, stream>>>(x0, out);
    // jac finalize
    jac_reduce<<<8, 64, 0, stream>>>(jpart, out);
}

// Round 6
// 778.589 us; speedup vs baseline: 1.6340x; 1.0337x over previous
//
#include <hip/hip_runtime.h>
#include <math.h>

typedef __bf16 bf16;
typedef __attribute__((ext_vector_type(8))) __bf16 bf16x8;
typedef __attribute__((ext_vector_type(4))) __bf16 bf16x4;
typedef __attribute__((ext_vector_type(4))) float floatx4;

#define MFMA16(a, b, c) __builtin_amdgcn_mfma_f32_16x16x32_bf16((a), (b), (c), 0, 0, 0)

__device__ __forceinline__ float bflo(unsigned d) {
    unsigned u = d << 16; float f; __builtin_memcpy(&f, &u, 4); return f;
}
__device__ __forceinline__ float bfhi(unsigned d) {
    unsigned u = d & 0xffff0000u; float f; __builtin_memcpy(&f, &u, 4); return f;
}

__device__ __forceinline__ void breduce1(float &a, float* lds, int t) {
    #pragma unroll
    for (int off = 32; off; off >>= 1) a += __shfl_xor(a, off, 64);
    __syncthreads();
    if ((t & 63) == 0) lds[t >> 6] = a;
    __syncthreads();
    a = lds[0] + lds[1] + lds[2] + lds[3];
}

// ---------------- init: copy res lower half --------------------------------
__global__ __launch_bounds__(256) void init_kernel(const float* __restrict__ x0,
                                                   float* __restrict__ out) {
    int fi = blockIdx.x * 256 + threadIdx.x;
    int b = fi >> 18;
    int r = fi & 262143;
    const float4* src = (const float4*)x0;
    float4* dst = (float4*)out;
    dst[(size_t)b * 524288 + r] = src[(size_t)b * 524288 + r];
}

// ---------------- weight fp32 -> bf16 hi/lo pairs (8 matrices) -------------
__global__ __launch_bounds__(256) void wconv(
    const float* __restrict__ w0, const float* __restrict__ w1,
    const float* __restrict__ w2, const float* __restrict__ w3,
    const float* __restrict__ w4, const float* __restrict__ w5,
    const float* __restrict__ w6, const float* __restrict__ w7,
    bf16* __restrict__ dst) {
    const int wi = blockIdx.y;
    const float* src = wi == 0 ? w0 : wi == 1 ? w1 : wi == 2 ? w2 : wi == 3 ? w3
                     : wi == 4 ? w4 : wi == 5 ? w5 : wi == 6 ? w6 : w7;
    const int i = blockIdx.x * 1024 + threadIdx.x * 4;
    const float4 v = *(const float4*)(src + i);
    bf16x4 h, l;
    #pragma unroll
    for (int j = 0; j < 4; j++) {
        const float f = ((const float*)&v)[j];
        const bf16 hb = (bf16)f;
        h[j] = hb;
        l[j] = (bf16)(f - (float)hb);
    }
    *(bf16x4*)(dst + (size_t)wi * 65536 + i) = h;
    *(bf16x4*)(dst + (size_t)(8 + wi) * 65536 + i) = l;
}

// ---------------- split-precision MFMA GEMM --------------------------------
// D[n][o] = A[n][k] * W[o][k]^T + bias.  tile 128n x 128o, K=256 in 8x32.
template <int MODE>
__global__ __launch_bounds__(256) void gemm_mfma(
    const void* __restrict__ Aptr, int ldA, long long bsA,
    const bf16* __restrict__ Whi, const bf16* __restrict__ Wlo,
    const float* __restrict__ bias,
    bf16* __restrict__ outb,
    float* outf,
    const float* __restrict__ x0full,
    float* __restrict__ jpart)
{
    constexpr bool ASPLIT = (MODE <= 2);
    __shared__ __align__(16) bf16 As_hi[128 * 40];
    __shared__ __align__(16) bf16 As_lo[ASPLIT ? 128 * 40 : 1];
    __shared__ __align__(16) bf16 Bs_hi[128 * 40];
    __shared__ __align__(16) bf16 Bs_lo[128 * 40];
    __shared__ float red[4];
    const int t = threadIdx.x;
    const int b = blockIdx.z;
    const int n0 = blockIdx.x * 128;
    const int o0 = blockIdx.y * 128;
    const int w = t >> 6, l = t & 63;
    const int wr = w & 1, wc = w >> 1;
    const int lr = l & 15, lq = l >> 4;

    floatx4 acc[4][4] = {};

    for (int kb = 0; kb < 8; kb++) {
        if (ASPLIT) {
            const float* Af = (const float*)Aptr + (size_t)b * bsA;
            #pragma unroll
            for (int s = 0; s < 4; s++) {
                const int kk = s * 8 + (t >> 5);
                const int n = (t & 31) * 4;
                const float4 v = *(const float4*)(Af + (size_t)(kb * 32 + kk) * ldA + n0 + n);
                #pragma unroll
                for (int j = 0; j < 4; j++) {
                    const float f = ((const float*)&v)[j];
                    const bf16 hb = (bf16)f;
                    As_hi[(n + j) * 40 + kk] = hb;
                    As_lo[(n + j) * 40 + kk] = (bf16)(f - (float)hb);
                }
            }
        } else {
            const bf16* Ab = (const bf16*)Aptr + (size_t)b * bsA;
            #pragma unroll
            for (int s = 0; s < 2; s++) {
                const int idx = t + 256 * s;
                const int row = idx >> 2, seg = idx & 3;
                *(bf16x8*)(As_hi + row * 40 + seg * 8) =
                    *(const bf16x8*)(Ab + (size_t)(n0 + row) * 256 + kb * 32 + seg * 8);
            }
        }
        #pragma unroll
        for (int s = 0; s < 2; s++) {
            const int idx = t + 256 * s;
            const int row = idx >> 2, seg = idx & 3;
            *(bf16x8*)(Bs_hi + row * 40 + seg * 8) =
                *(const bf16x8*)(Whi + (size_t)(o0 + row) * 256 + kb * 32 + seg * 8);
            *(bf16x8*)(Bs_lo + row * 40 + seg * 8) =
                *(const bf16x8*)(Wlo + (size_t)(o0 + row) * 256 + kb * 32 + seg * 8);
        }
        __syncthreads();
        bf16x8 ah[4], al[4], bh[4], bl[4];
        #pragma unroll
        for (int f = 0; f < 4; f++) {
            ah[f] = *(const bf16x8*)(As_hi + (wr * 64 + f * 16 + lr) * 40 + lq * 8);
            if (ASPLIT)
                al[f] = *(const bf16x8*)(As_lo + (wr * 64 + f * 16 + lr) * 40 + lq * 8);
            bh[f] = *(const bf16x8*)(Bs_hi + (wc * 64 + f * 16 + lr) * 40 + lq * 8);
            bl[f] = *(const bf16x8*)(Bs_lo + (wc * 64 + f * 16 + lr) * 40 + lq * 8);
        }
        #pragma unroll
        for (int i = 0; i < 4; i++)
            #pragma unroll
            for (int j = 0; j < 4; j++) {
                acc[i][j] = MFMA16(ah[i], bh[j], acc[i][j]);
                acc[i][j] = MFMA16(ah[i], bl[j], acc[i][j]);
                if (ASPLIT) acc[i][j] = MFMA16(al[i], bh[j], acc[i][j]);
            }
        __syncthreads();
    }

    float ssum = 0.0f;
    #pragma unroll
    for (int i = 0; i < 4; i++) {
        #pragma unroll
        for (int j = 0; j < 4; j++) {
            const int o_g = o0 + wc * 64 + j * 16 + lr;
            const int n_b = n0 + wr * 64 + i * 16 + lq * 4;
            const float bia = bias[o_g];
            floatx4 val = acc[i][j];
            val[0] += bia; val[1] += bia; val[2] += bia; val[3] += bia;
            if (MODE == 0) {
                *(floatx4*)(outf + (size_t)b * 2097152 + (size_t)o_g * 4096 + n_b) = val;
                #pragma unroll
                for (int r = 0; r < 4; r++)
                    outb[((size_t)b * 4096 + n_b + r) * 256 + o_g] = (bf16)val[r];
            } else if (MODE == 1) {
                #pragma unroll
                for (int r = 0; r < 4; r++)
                    outb[((size_t)b * 256 + n_b + r) * 256 + o_g] = (bf16)val[r];
            } else if (MODE == 2) {
                bf16x4 pv;
                pv[0] = (bf16)val[0]; pv[1] = (bf16)val[1];
                pv[2] = (bf16)val[2]; pv[3] = (bf16)val[3];
                *(bf16x4*)(outb + ((size_t)b * 256 + o_g) * 256 + n_b) = pv;
            } else {
                const size_t addr = (size_t)b * 2097152 + (size_t)(256 + o_g) * 4096 + n_b;
                if (MODE == 3) {
                    *(floatx4*)(outf + addr) = val;
                } else {
                    const floatx4 s4 = *(const floatx4*)(outf + addr);
                    const floatx4 x4 = *(const floatx4*)(x0full + addr);
                    floatx4 res;
                    #pragma unroll
                    for (int r = 0; r < 4; r++) res[r] = x4[r] * expf(s4[r]) + val[r];
                    *(floatx4*)(outf + addr) = res;
                    ssum += s4[0] + s4[1] + s4[2] + s4[3];
                }
            }
        }
    }
    if (MODE == 4) {
        breduce1(ssum, red, t);
        if (t == 0) jpart[b * 64 + blockIdx.y * 32 + blockIdx.x] = ssum;
    }
}

// ---------------- jac finalize ---------------------------------------------
__global__ __launch_bounds__(64) void jac_reduce(const float* __restrict__ jpart,
                                                 float* __restrict__ out) {
    const int b = blockIdx.x, t = threadIdx.x;
    float v = jpart[b * 64 + t];
    #pragma unroll
    for (int off = 32; off; off >>= 1) v += __shfl_xor(v, off, 64);
    if (t == 0) out[16777216 + b] = v;
}

// ---------------- offset branch (q fp32 lives in out-lower) ----------------
__global__ __launch_bounds__(256) void offset_kernel(
    const float* __restrict__ q,
    const float* __restrict__ dw_w, const float* __restrict__ dw_b,
    const float* __restrict__ ln_g, const float* __restrict__ ln_b,
    const float* __restrict__ pw_w,
    float* __restrict__ pos)
{
    __shared__ float red[8];
    const int wk = blockIdx.x, hk = blockIdx.y, b = blockIdx.z;
    const int c = threadIdx.x;
    const float* qp = q + (size_t)b * 2097152 + (size_t)c * 4096 + (hk * 4) * 64 + wk * 4;
    float accv = dw_b[c];
    #pragma unroll
    for (int p = 0; p < 4; p++) {
        const float4 r = *(const float4*)(qp + p * 64);
        const float4 w = *(const float4*)(dw_w + c * 16 + p * 4);
        accv += r.x * w.x + r.y * w.y + r.z * w.z + r.w * w.w;
    }
    float a = accv, sq = accv * accv;
    #pragma unroll
    for (int off = 32; off; off >>= 1) {
        a += __shfl_xor(a, off, 64);
        sq += __shfl_xor(sq, off, 64);
    }
    __syncthreads();
    if ((c & 63) == 0) { red[c >> 6] = a; red[4 + (c >> 6)] = sq; }
    __syncthreads();
    a = red[0] + red[1] + red[2] + red[3];
    sq = red[4] + red[5] + red[6] + red[7];
    const float mu = a * (1.0f / 256.0f);
    const float var = sq * (1.0f / 256.0f) - mu * mu;
    float nrm = (accv - mu) * rsqrtf(var + 1e-5f) * ln_g[c] + ln_b[c];
    const float act = 0.5f * nrm * (1.0f + erff(nrm * 0.70710678118654752f));
    float v0 = pw_w[c] * act;
    float v1 = pw_w[256 + c] * act;
    #pragma unroll
    for (int off = 32; off; off >>= 1) {
        v0 += __shfl_xor(v0, off, 64);
        v1 += __shfl_xor(v1, off, 64);
    }
    __syncthreads();
    if ((c & 63) == 0) { red[c >> 6] = v0; red[4 + (c >> 6)] = v1; }
    __syncthreads();
    if (c == 0) {
        v0 = red[0] + red[1] + red[2] + red[3];
        v1 = red[4] + red[5] + red[6] + red[7];
        const float refy = (0.5f + hk) * (2.0f / 15.0f) - 1.0f;
        const float refx = (0.5f + wk) * (2.0f / 15.0f) - 1.0f;
        const float py = fminf(fmaxf(v0 + refy, -1.0f), 1.0f);
        const float px = fminf(fmaxf(v1 + refx, -1.0f), 1.0f);
        const int n = hk * 16 + wk;
        pos[(b * 256 + n) * 2] = py;
        pos[(b * 256 + n) * 2 + 1] = px;
    }
}

// ---------------- bilinear sample -> xs fp32 channel-major [b][c][n] -------
// one block per (n, b): 4 waves -> high TLP for the latency-bound gather
__global__ __launch_bounds__(256) void sample_kernel(
    const float* __restrict__ x0,
    const float* __restrict__ pos,
    float* __restrict__ xs)
{
    const int c = threadIdx.x, n = blockIdx.x, b = blockIdx.y;
    const float py = pos[(b * 256 + n) * 2];
    const float px = pos[(b * 256 + n) * 2 + 1];
    const float x = (px + 1.0f) * 31.5f;
    const float y = (py + 1.0f) * 31.5f;
    const float xf = floorf(x), yf = floorf(y);
    const float wx = x - xf, wy = y - yf;
    const int xi0 = min(max((int)xf, 0), 63);
    const int xi1 = min(xi0 + 1, 63);
    const int yi0 = min(max((int)yf, 0), 63);
    const int yi1 = min(yi0 + 1, 63);
    const float* base = x0 + (size_t)b * 2097152 + (size_t)c * 4096;
    const float v00 = base[yi0 * 64 + xi0], v01 = base[yi0 * 64 + xi1];
    const float v10 = base[yi1 * 64 + xi0], v11 = base[yi1 * 64 + xi1];
    xs[((size_t)b * 256 + c) * 256 + n] =
        v00 * (1 - wx) * (1 - wy) + v01 * wx * (1 - wy) +
        v10 * (1 - wx) * wy + v11 * wx * wy;
}

// ---------------- fused MFMA attention -------------------------------------
// Block = (query row my=blockIdx.x, head, batch). RPE bilinear has constant
// fractional weights per n (integer-shift structure): stage y-blended rows
// R[n][0..64] in pl's LDS space (coalesced), bias = 1D lerp from R.
__global__ __launch_bounds__(256) void attn_mfma(
    const bf16* qbfT,               // [b][4096][256]
    const bf16* __restrict__ kT,    // [b][256][256] pixel-major
    const bf16* __restrict__ vb,    // [b][256 c][256 n] channel-major
    const float* __restrict__ pos,
    const float* __restrict__ rpe,
    bf16* obfT)                     // aliases qbfT
{
    __shared__ __align__(16) bf16 kvt[18432];      // K: [256 n][72] / V: [64 c][264]
    __shared__ __align__(16) bf16 pl[16896];       // R: [256 n][66] then P: [4][16][264]
    __shared__ float posy[256], posx[256], wxs[256];
    const int t = threadIdx.x;
    const int w = t >> 6, l = t & 63;
    const int lr = l & 15, lq = l >> 4;
    const int m_base = blockIdx.x * 64 + w * 16;
    const int my = blockIdx.x;          // m>>6, constant per block
    const int h = blockIdx.y, b = blockIdx.z;

    posy[t] = pos[(b * 256 + t) * 2];
    posx[t] = pos[(b * 256 + t) * 2 + 1];

    // Q fragments
    const bf16* qrow = qbfT + ((size_t)b * 4096 + m_base + lr) * 256 + h * 64;
    bf16x8 qf0 = *(const bf16x8*)(qrow + lq * 8);
    bf16x8 qf1 = *(const bf16x8*)(qrow + 32 + lq * 8);

    // stage K tile
    #pragma unroll
    for (int i = 0; i < 8; i++) {
        const int idx = t + 256 * i;
        const int n = idx >> 3, seg = idx & 7;
        *(bf16x8*)(kvt + n * 72 + seg * 8) =
            *(const bf16x8*)(kT + ((size_t)b * 256 + n) * 256 + h * 64 + seg * 8);
    }

    // stage R: wave w handles n in [w*64, w*64+64) (its own posx/posy range)
    const float* rp = rpe + h * 16129;
    #pragma unroll 4
    for (int i = 0; i < 64; i++) {
        const int n = w * 64 + i;
        const float yy = (float)my + 63.0f - 31.5f * posy[n];
        const float xoffv = 63.0f - 31.5f * posx[n];
        const float yfl = floorf(yy);
        const float wy = yy - yfl;
        const int y0 = min((int)yfl, 126);
        const int y1 = min(y0 + 1, 126);
        const int xb = (int)floorf(xoffv);
        if (l == 0) wxs[n] = xoffv - floorf(xoffv);
        const int xj = min(xb + l, 126);
        const float v0 = rp[y0 * 127 + xj];
        const float v1 = rp[y1 * 127 + xj];
        pl[n * 66 + l] = (bf16)(v0 + wy * (v1 - v0));
        if (l == 63) {
            const int xe = min(xb + 64, 126);
            const float e0 = rp[y0 * 127 + xe];
            const float e1 = rp[y1 * 127 + xe];
            pl[n * 66 + 64] = (bf16)(e0 + wy * (e1 - e0));
        }
    }
    __syncthreads();

    // QK^T
    floatx4 lg[16];
    #pragma unroll
    for (int nf = 0; nf < 16; nf++) {
        const bf16x8 k0 = *(const bf16x8*)(kvt + (nf * 16 + lr) * 72 + lq * 8);
        const bf16x8 k1 = *(const bf16x8*)(kvt + (nf * 16 + lr) * 72 + 32 + lq * 8);
        floatx4 a = {};
        a = MFMA16(qf0, k0, a);
        a = MFMA16(qf1, k1, a);
        lg[nf] = a;
    }

    // bias from R: thread covers m-cols mx = w*16+lq*4 .. +3 (4-byte aligned dwords)
    #pragma unroll
    for (int nf = 0; nf < 16; nf++) {
        const int n = nf * 16 + lr;
        const unsigned* rw = (const unsigned*)(pl + n * 66 + w * 16 + lq * 4);
        const unsigned d0 = rw[0], d1 = rw[1], d2 = rw[2];
        float rv[5];
        rv[0] = bflo(d0); rv[1] = bfhi(d0);
        rv[2] = bflo(d1); rv[3] = bfhi(d1);
        rv[4] = bflo(d2);
        const float wxv = wxs[n];
        #pragma unroll
        for (int r = 0; r < 4; r++)
            lg[nf][r] = lg[nf][r] * 0.125f + (rv[r] + wxv * (rv[r + 1] - rv[r]));
    }

    // softmax per row (16 lanes share a row)
    float mx[4], inv[4];
    #pragma unroll
    for (int r = 0; r < 4; r++) {
        float m = -1e30f;
        #pragma unroll
        for (int nf = 0; nf < 16; nf++) m = fmaxf(m, lg[nf][r]);
        #pragma unroll
        for (int off = 1; off < 16; off <<= 1) m = fmaxf(m, __shfl_xor(m, off, 64));
        mx[r] = m;
    }
    #pragma unroll
    for (int r = 0; r < 4; r++) {
        float s = 0.0f;
        #pragma unroll
        for (int nf = 0; nf < 16; nf++) {
            const float e = expf(lg[nf][r] - mx[r]);
            lg[nf][r] = e;
            s += e;
        }
        #pragma unroll
        for (int off = 1; off < 16; off <<= 1) s += __shfl_xor(s, off, 64);
        inv[r] = 1.0f / s;
    }

    __syncthreads();   // all waves done reading R (pl) and K (kvt)

    // P (scaled) -> bf16 LDS, wave-private [16 m][264 n]; V tile -> kvt
    bf16* plw = pl + w * 16 * 264;
    #pragma unroll
    for (int nf = 0; nf < 16; nf++)
        #pragma unroll
        for (int r = 0; r < 4; r++)
            plw[(lq * 4 + r) * 264 + nf * 16 + lr] = (bf16)(lg[nf][r] * inv[r]);

    #pragma unroll
    for (int i = 0; i < 8; i++) {
        const int idx = t + 256 * i;
        const int c = idx >> 5, seg = idx & 31;
        *(bf16x8*)(kvt + c * 264 + seg * 8) =
            *(const bf16x8*)(vb + ((size_t)b * 256 + h * 64 + c) * 256 + seg * 8);
    }
    __syncthreads();

    // PV
    floatx4 oc[4] = {};
    #pragma unroll
    for (int kf = 0; kf < 8; kf++) {
        const bf16x8 pa = *(const bf16x8*)(plw + lr * 264 + kf * 32 + lq * 8);
        #pragma unroll
        for (int j = 0; j < 4; j++) {
            const bf16x8 vf = *(const bf16x8*)(kvt + (j * 16 + lr) * 264 + kf * 32 + lq * 8);
            oc[j] = MFMA16(pa, vf, oc[j]);
        }
    }

    #pragma unroll
    for (int j = 0; j < 4; j++)
        #pragma unroll
        for (int r = 0; r < 4; r++)
            obfT[((size_t)b * 4096 + m_base + lq * 4 + r) * 256 + h * 64 + j * 16 + lr]
                = (bf16)oc[j][r];
}

// ---------------- host launcher --------------------------------------------
extern "C" void kernel_launch(void* const* d_in, const int* in_sizes, int n_in,
                              void* d_out, int out_size, void* d_ws, size_t ws_size,
                              hipStream_t stream) {
    const float* x0 = (const float*)d_in[0];
    float* out = (float*)d_out;
    float* ws = (float*)d_ws;
    // ws layout (float units), total ~23.1 MB
    bf16* qbfT  = (bf16*)ws;                   // [8][4096][256] bf16 = 4,194,304 fl
    float* xsT  = ws + 4194304;                // [8][256][256] fp32  =   524,288 fl
    bf16* kTb   = (bf16*)(ws + 4718592);       // [8][256][256] bf16  =   262,144 fl
    bf16* vbb   = (bf16*)(ws + 4980736);       // [8][256][256] bf16  =   262,144 fl
    bf16* wbf   = (bf16*)(ws + 5242880);       // 16 x [256][256] bf16=   524,288 fl
    float* pos  = ws + 5767168;                // 4,096 fl
    float* jpart= ws + 5771264;                // 512 fl  (end 5,771,776)

    wconv<<<dim3(64, 8), 256, 0, stream>>>(
        (const float*)d_in[6], (const float*)d_in[8], (const float*)d_in[10],
        (const float*)d_in[12], (const float*)d_in[20], (const float*)d_in[22],
        (const float*)d_in[24], (const float*)d_in[26], wbf);

    for (int pass = 0; pass < 2; pass++) {
        const int pb = 1 + 14 * pass;
        const float* dw_w = (const float*)d_in[pb + 0];
        const float* dw_b = (const float*)d_in[pb + 1];
        const float* ln_g = (const float*)d_in[pb + 2];
        const float* ln_b = (const float*)d_in[pb + 3];
        const float* pw_w = (const float*)d_in[pb + 4];
        const float* bq   = (const float*)d_in[pb + 6];
        const float* bk   = (const float*)d_in[pb + 8];
        const float* bv   = (const float*)d_in[pb + 10];
        const float* bo   = (const float*)d_in[pb + 12];
        const float* rpe  = (const float*)d_in[pb + 13];
        const bf16* wq_h = wbf + (size_t)(pass * 4 + 0) * 65536;
        const bf16* wk_h = wbf + (size_t)(pass * 4 + 1) * 65536;
        const bf16* wv_h = wbf + (size_t)(pass * 4 + 2) * 65536;
        const bf16* wo_h = wbf + (size_t)(pass * 4 + 3) * 65536;
        const bf16* wq_l = wq_h + 8 * 65536;
        const bf16* wk_l = wk_h + 8 * 65536;
        const bf16* wv_l = wv_h + 8 * 65536;
        const bf16* wo_l = wo_h + 8 * 65536;

        gemm_mfma<0><<<dim3(32, 2, 8), 256, 0, stream>>>(
            x0, 4096, 2097152LL, wq_h, wq_l, bq, qbfT, out, nullptr, nullptr);
        offset_kernel<<<dim3(16, 16, 8), 256, 0, stream>>>(
            out, dw_w, dw_b, ln_g, ln_b, pw_w, pos);
        sample_kernel<<<dim3(256, 8), 256, 0, stream>>>(x0, pos, xsT);
        gemm_mfma<1><<<dim3(2, 2, 8), 256, 0, stream>>>(
            xsT, 256, 65536LL, wk_h, wk_l, bk, kTb, nullptr, nullptr, nullptr);
        gemm_mfma<2><<<dim3(2, 2, 8), 256, 0, stream>>>(
            xsT, 256, 65536LL, wv_h, wv_l, bv, vbb, nullptr, nullptr, nullptr);
        attn_mfma<<<dim3(64, 4, 8), 256, 0, stream>>>(
            qbfT, kTb, vbb, pos, rpe, qbfT);
        if (pass == 0)
            gemm_mfma<3><<<dim3(32, 2, 8), 256, 0, stream>>>(
                qbfT, 256, 1048576LL, wo_h, wo_l, bo, nullptr, out, nullptr, nullptr);
        else
            gemm_mfma<4><<<dim3(32, 2, 8), 256, 0, stream>>>(
                qbfT, 256, 1048576LL, wo_h, wo_l, bo, nullptr, out, x0, jpart);
    }
    init_kernel<<<8192, 256, 0, stream>>>(x0, out);
    jac_reduce<<<8, 64, 0, stream>>>(jpart, out);
}